// Round 13
// baseline (183.263 us; speedup 1.0000x reference)
//
#include <hip/hip_runtime.h>
#include <stdint.h>

#define N_  32
#define C_  128
#define H_  56
#define W_  56
#define HW_ 3136
#define P_  128

using i32x4 = __attribute__((ext_vector_type(4))) int;

// ws layout (bytes), big-workspace path:
//   act : 32*58*8704 = 16,154,624  (pre-swizzled NHWC i8 rows, halo rows 0/57)
//   wI8 : P*1152     = 147,456
//   inv : P*4 ; b0 : P*4
#define ACT_ROWB   8704
#define ACT_NROWS  58
#define ACT_BYTES  ((size_t)N_ * ACT_NROWS * ACT_ROWB)
#define WI8_BYTES  (P_*1152)

// ------- pack weights to i8 +1/-1 in [p][t*128+c] layout; fold BN ------------
__global__ __launch_bounds__(256) void wpack_kernel(const float* __restrict__ weight,
        const float* __restrict__ bias, const float* __restrict__ gamma,
        const float* __restrict__ beta, const float* __restrict__ mean,
        const float* __restrict__ var,
        uint32_t* __restrict__ wI8, float* __restrict__ invG, float* __restrict__ b0G) {
    int gid = blockIdx.x * 256 + threadIdx.x;        // 144 blocks = 36864 dwords
    int p   = gid / 288;
    int rem = gid % 288;
    int k   = rem * 4;                               // k = t*128 + c
    int tp  = k >> 7;
    int c   = k & 127;
    uint32_t d = 0;
    #pragma unroll
    for (int i2 = 0; i2 < 4; ++i2) {
        float v = weight[((size_t)p * C_ + c + i2) * 9 + tp];
        uint32_t by = (v >= 0.f) ? 0x01u : 0xFFu;
        d |= by << (8 * i2);
    }
    wI8[gid] = d;
    if (blockIdx.x == 0 && threadIdx.x < P_) {
        int pp = threadIdx.x;
        float inv = gamma[pp] * rsqrtf(var[pp] + 1e-5f);
        invG[pp] = inv;
        b0G[pp]  = bias[pp] * inv + beta[pp] - mean[pp] * inv;
    }
}

// ------- pack_act: x (NCHW f32) -> pre-swizzled NHWC i8 rows + halo ---------
// (verified R12) One block per (n, rowIdx 0..57); rowIdx 0/57 zero halo.
__global__ __launch_bounds__(256) void pack_act(const float* __restrict__ x,
                                                uint8_t* __restrict__ act) {
    __shared__ uint32_t S[56 * 33];      // [w][c4] dwords, +1 pad per row
    int bid = blockIdx.x;
    int n   = bid / ACT_NROWS, ridx = bid % ACT_NROWS;
    int tid = threadIdx.x;
    uint8_t* rowG = act + (size_t)bid * ACT_ROWB;
    if (ridx == 0 || ridx == ACT_NROWS - 1) {
        #pragma unroll
        for (int j = 0; j < 3; ++j) {
            int k = j * 256 + tid;
            if (k < 544) *(uint4*)(rowG + (size_t)k * 16) = make_uint4(0u,0u,0u,0u);
        }
        return;
    }
    int h = ridx - 1;
    const uint32_t* xb = (const uint32_t*)x + (size_t)n * C_ * HW_ + h * W_;
    #pragma unroll
    for (int j = 0; j < 7; ++j) {        // 7*256 = 1792 = 32 c4-groups x 56 w
        int u  = j * 256 + tid;
        int c4 = u / 56;
        int w  = u - c4 * 56;
        const uint32_t* p = xb + (size_t)(c4 * 4) * HW_ + w;
        uint32_t s = (p[0] >> 31) | ((p[HW_] >> 31) << 8)
                   | ((p[2 * HW_] >> 31) << 16) | ((p[3 * HW_] >> 31) << 24);
        S[w * 33 + c4] = 0x01010101u + s * 0xFEu;
    }
    __syncthreads();
    #pragma unroll
    for (int j = 0; j < 3; ++j) {
        int k = j * 256 + tid;
        if (k < 544) {
            int colL = k >> 3, cb = k & 7;
            uint4 v = make_uint4(0u, 0u, 0u, 0u);
            if (colL >= 1 && colL <= 56) {
                int w = colL - 1;
                v.x = S[w * 33 + cb * 4 + 0];
                v.y = S[w * 33 + cb * 4 + 1];
                v.z = S[w * 33 + cb * 4 + 2];
                v.w = S[w * 33 + cb * 4 + 3];
            }
            int slot = cb ^ (colL & 7);
            *(uint4*)(rowG + (size_t)(colL * 8 + slot) * 16) = v;
        }
    }
}

// ------- bconv_pipe: 2 row-pair tiles per block over a 6-slot LDS ring ------
// T3/T4 counted-vmcnt pipeline (enabled by R12's DMA staging):
//   issue DMA slots 0-3, sched_barrier, issue DMA slots 4-5, sched_barrier,
//   per-wave s_waitcnt vmcnt(5|4) (phase-2 count) + raw s_barrier
//   -> tile-1 staging stays IN FLIGHT across the barrier, hidden under
//   tile-0's taps + epilogue. Mid-block: plain __syncthreads (phase-2 long
//   retired). Ring shares 2 rows: DMA traffic -25%; grid 448 (8-bijective).
// Per-tap main loop / epilogue / XCD chunking identical to verified R12.
// LDS 53,248B -> 3 blocks/CU. Tripwires: VGPR<=168, WRITE~52-57MB.
__global__ __launch_bounds__(256) void bconv_pipe(
        const uint4* __restrict__ wI8v,
        const float* __restrict__ invG, const float* __restrict__ b0G,
        const uint8_t* __restrict__ act,
        const float* __restrict__ x, float* __restrict__ out) {
    __shared__ uint4 actT[6 * 68 * 8];   // 52,224B ring: [slot][colL][chunk]
    __shared__ float sInv[P_], sB0[P_];

    int tid = threadIdx.x;
    // XCD-chunked swizzle; 448 % 8 == 0 (bijective), 56 blocks/XCD.
    int bid  = (blockIdx.x & 7) * 56 + (blockIdx.x >> 3);
    int img  = bid / 14;
    int quad = bid % 14;
    int r0b  = quad * 4;                 // 4 output rows per block

    int lane = tid & 63;
    int wi   = tid >> 6;
    int q    = lane >> 4;
    int l15  = lane & 15;
    int m0   = wi * 32;

    // sInv/sB0 staging FIRST (its ds_write drains only its own 2 loads)
    if (tid < P_) { sInv[tid] = invG[tid]; sB0[tid] = b0G[tid]; }

    // ---- issue ALL staging DMA up front (order-pinned) ---------------------
    const uint8_t* actG = act + (size_t)img * ACT_NROWS * ACT_ROWB
                              + (size_t)r0b * ACT_ROWB;
    // phase 1: slots 0-3 (2176 chunks = 34 full waves)
    #pragma unroll
    for (int i = 0; i < 9; ++i) {
        int cid = i * 256 + tid;
        if (cid < 2176)
            __builtin_amdgcn_global_load_lds(
                (const uint32_t*)(actG + (size_t)cid * 16),
                (uint32_t*)&actT[cid], 16, 0, 0);
    }
    __builtin_amdgcn_sched_barrier(0);   // pin phase-1 before phase-2
    // phase 2: slots 4-5 (1088 chunks = 17 full waves)
    #pragma unroll
    for (int i = 0; i < 5; ++i) {
        int cid = i * 256 + tid;
        if (cid < 1088)
            __builtin_amdgcn_global_load_lds(
                (const uint32_t*)(actG + (size_t)(2176 + cid) * 16),
                (uint32_t*)&actT[2176 + cid], 16, 0, 0);
    }
    __builtin_amdgcn_sched_barrier(0);   // pin issue order vs the counted wait

    // counted wait: outstanding <= per-wave phase-2 count (w0:5, w1-3:4)
    // -> phase-1 retired, phase-2 STILL IN FLIGHT across the barrier.
    if (wi == 0) asm volatile("s_waitcnt vmcnt(5) lgkmcnt(0)" ::: "memory");
    else         asm volatile("s_waitcnt vmcnt(4) lgkmcnt(0)" ::: "memory");
    __builtin_amdgcn_s_barrier();
    __builtin_amdgcn_sched_barrier(0);

    #pragma unroll 1
    for (int tt = 0; tt < 2; ++tt) {
        int so = tt * 2;                 // ring slot offset for this tile
        int r0 = r0b + tt * 2;           // this tile's first output row

        // tap-0 weight prefetch (L2-hot), double-buffered across taps
        i32x4 aw[2][2][2];               // [buf][mi][ks]
        #pragma unroll
        for (int mi = 0; mi < 2; ++mi)
            #pragma unroll
            for (int ks = 0; ks < 2; ++ks)
                aw[0][mi][ks] = *(const i32x4*)&wI8v[(size_t)(m0 + mi*16 + l15) * 72
                                                     + ks * 4 + q];

        i32x4 acc[2][8];
        #pragma unroll
        for (int mi = 0; mi < 2; ++mi)
            #pragma unroll
            for (int j = 0; j < 8; ++j)
                #pragma unroll
                for (int e = 0; e < 4; ++e) acc[mi][j][e] = 0;

        for (int t9 = 0; t9 < 9; ++t9) {
            int nb = t9 & 1;
            if (t9 < 8) {                // prefetch next tap's weights
                #pragma unroll
                for (int mi = 0; mi < 2; ++mi)
                    #pragma unroll
                    for (int ks = 0; ks < 2; ++ks)
                        aw[nb ^ 1][mi][ks] = *(const i32x4*)&wI8v[(size_t)(m0 + mi*16 + l15) * 72
                                                                  + (t9 + 1) * 8 + ks * 4 + q];
            }
            int dh = t9 / 3, dw = t9 % 3;
            #pragma unroll
            for (int ks = 0; ks < 2; ++ks) {
                #pragma unroll
                for (int j = 0; j < 8; ++j) {
                    int n    = j * 16 + l15;
                    int colL = (n & 63) + dw;
                    int slot = (n >> 6) + dh + so;
                    i32x4 bf = *(const i32x4*)&actT[(slot * 68 + colL) * 8
                                                    + ((ks * 4 + q) ^ (colL & 7))];
                    acc[0][j] = __builtin_amdgcn_mfma_i32_16x16x64_i8(aw[nb][0][ks], bf, acc[0][j], 0, 0, 0);
                    acc[1][j] = __builtin_amdgcn_mfma_i32_16x16x64_i8(aw[nb][1][ks], bf, acc[1][j], 0, 0, 0);
                }
            }
        }

        // ---- epilogue: BN + residual, coalesced 64B segments ----
        #pragma unroll
        for (int j = 0; j < 8; ++j) {
            int n = j * 16 + l15;
            int w = n & 63;
            if (w < W_) {
                int orow = r0 + (n >> 6);
                size_t pixOff = (size_t)img * P_ * HW_ + (size_t)orow * W_ + w;
                #pragma unroll
                for (int mi = 0; mi < 2; ++mi)
                    #pragma unroll
                    for (int reg = 0; reg < 4; ++reg) {
                        int m = m0 + mi * 16 + q * 4 + reg;
                        size_t off = pixOff + (size_t)m * HW_;
                        out[off] = (float)acc[mi][j][reg] * sInv[m] + sB0[m] + x[off];
                    }
            }
        }

        if (tt == 0) __syncthreads();    // phase-2 long retired; cheap drain
    }
}

// ------- fallback: R7 fused kernel (verified 56.7us) -- used if ws too small -
__global__ __launch_bounds__(256) void bconv_fused(
        const uint4* __restrict__ wI8v,
        const float* __restrict__ invG, const float* __restrict__ b0G,
        const float* __restrict__ x, float* __restrict__ out) {
    __shared__ uint4 actT[4 * 68 * 8];
    __shared__ float sInv[P_], sB0[P_];

    int tid = threadIdx.x;
    int bid = (blockIdx.x & 7) * 112 + (blockIdx.x >> 3);
    int img = bid / 28;
    int rp  = bid % 28;
    int r0  = rp * 2;

    int lane = tid & 63;
    int wi   = tid >> 6;
    int q    = lane >> 4;
    int l15  = lane & 15;
    int m0   = wi * 32;

    if (tid < P_) { sInv[tid] = invG[tid]; sB0[tid] = b0G[tid]; }

    i32x4 aw[2][2][2];
    #pragma unroll
    for (int mi = 0; mi < 2; ++mi)
        #pragma unroll
        for (int ks = 0; ks < 2; ++ks)
            aw[0][mi][ks] = *(const i32x4*)&wI8v[(size_t)(m0 + mi*16 + l15) * 72
                                                 + ks * 4 + q];

    if (tid < 224) {
        int rho = tid / 56;
        int rr2 = tid % 56;
        int cg  = rr2 / 14;
        int tq  = rr2 % 14;
        int h   = r0 - 1 + rho;
        bool vh = ((unsigned)h < (unsigned)H_);
        uint32_t c0 = vh ? 0x01010101u : 0u;
        uint32_t cf = vh ? 0xFEu       : 0u;
        const uint32_t* xb = (const uint32_t*)x
            + ((size_t)img * C_ + cg * 32) * HW_ + (vh ? h : 0) * W_ + tq * 4;
        int colL0 = tq * 4 + 1;
        #pragma unroll
        for (int ph = 0; ph < 2; ++ph) {
            uint32_t cell0[4], cell1[4], cell2[4], cell3[4];
            #pragma unroll
            for (int d = 0; d < 4; ++d) {
                uint32_t w0 = 0, w1 = 0, w2 = 0, w3 = 0;
                if (vh) {
                    #pragma unroll
                    for (int i = 0; i < 4; ++i) {
                        uint4 u = *(const uint4*)(xb + (size_t)(ph * 16 + d * 4 + i) * HW_);
                        uint32_t sh = i * 8;
                        w0 |= (u.x >> 31) << sh;
                        w1 |= (u.y >> 31) << sh;
                        w2 |= (u.z >> 31) << sh;
                        w3 |= (u.w >> 31) << sh;
                    }
                }
                cell0[d] = c0 + w0 * cf;
                cell1[d] = c0 + w1 * cf;
                cell2[d] = c0 + w2 * cf;
                cell3[d] = c0 + w3 * cf;
            }
            int cb = cg * 2 + ph;
            actT[(rho * 68 + colL0 + 0) * 8 + (cb ^ ((colL0 + 0) & 7))] =
                make_uint4(cell0[0], cell0[1], cell0[2], cell0[3]);
            actT[(rho * 68 + colL0 + 1) * 8 + (cb ^ ((colL0 + 1) & 7))] =
                make_uint4(cell1[0], cell1[1], cell1[2], cell1[3]);
            actT[(rho * 68 + colL0 + 2) * 8 + (cb ^ ((colL0 + 2) & 7))] =
                make_uint4(cell2[0], cell2[1], cell2[2], cell2[3]);
            actT[(rho * 68 + colL0 + 3) * 8 + (cb ^ ((colL0 + 3) & 7))] =
                make_uint4(cell3[0], cell3[1], cell3[2], cell3[3]);
        }
    } else {
        int z = tid - 224;
        #pragma unroll
        for (int rep = 0; rep < 2; ++rep) {
            int e = z + rep * 32;
            if (e < 48) {
                int rho  = e / 12;
                int jj   = e % 12;
                int colL = jj ? (56 + jj) : 0;
                int base = (rho * 68 + colL) * 8;
                #pragma unroll
                for (int s = 0; s < 8; ++s) actT[base + s] = make_uint4(0u,0u,0u,0u);
            }
        }
    }

    __syncthreads();

    i32x4 acc[2][8];
    #pragma unroll
    for (int mi = 0; mi < 2; ++mi)
        #pragma unroll
        for (int j = 0; j < 8; ++j)
            #pragma unroll
            for (int e = 0; e < 4; ++e) acc[mi][j][e] = 0;

    for (int t9 = 0; t9 < 9; ++t9) {
        int nb = t9 & 1;
        if (t9 < 8) {
            #pragma unroll
            for (int mi = 0; mi < 2; ++mi)
                #pragma unroll
                for (int ks = 0; ks < 2; ++ks)
                    aw[nb ^ 1][mi][ks] = *(const i32x4*)&wI8v[(size_t)(m0 + mi*16 + l15) * 72
                                                              + (t9 + 1) * 8 + ks * 4 + q];
        }
        int dh = t9 / 3, dw = t9 % 3;
        #pragma unroll
        for (int ks = 0; ks < 2; ++ks) {
            #pragma unroll
            for (int j = 0; j < 8; ++j) {
                int n    = j * 16 + l15;
                int colL = (n & 63) + dw;
                int rho  = (n >> 6) + dh;
                i32x4 bf = *(const i32x4*)&actT[(rho * 68 + colL) * 8 + ((ks * 4 + q) ^ (colL & 7))];
                acc[0][j] = __builtin_amdgcn_mfma_i32_16x16x64_i8(aw[nb][0][ks], bf, acc[0][j], 0, 0, 0);
                acc[1][j] = __builtin_amdgcn_mfma_i32_16x16x64_i8(aw[nb][1][ks], bf, acc[1][j], 0, 0, 0);
            }
        }
    }

    #pragma unroll
    for (int j = 0; j < 8; ++j) {
        int n = j * 16 + l15;
        int w = n & 63;
        if (w < W_) {
            int orow = r0 + (n >> 6);
            size_t pixOff = (size_t)img * P_ * HW_ + (size_t)orow * W_ + w;
            #pragma unroll
            for (int mi = 0; mi < 2; ++mi)
                #pragma unroll
                for (int reg = 0; reg < 4; ++reg) {
                    int m = m0 + mi * 16 + q * 4 + reg;
                    size_t off = pixOff + (size_t)m * HW_;
                    out[off] = (float)acc[mi][j][reg] * sInv[m] + sB0[m] + x[off];
                }
        }
    }
}

extern "C" void kernel_launch(void* const* d_in, const int* in_sizes, int n_in,
                              void* d_out, int out_size, void* d_ws, size_t ws_size,
                              hipStream_t stream) {
    const float* x      = (const float*)d_in[0];
    const float* weight = (const float*)d_in[1];
    const float* bias   = (const float*)d_in[2];
    const float* gamma  = (const float*)d_in[3];
    const float* beta   = (const float*)d_in[4];
    const float* mean   = (const float*)d_in[5];
    const float* var    = (const float*)d_in[6];
    float* out = (float*)d_out;

    uint8_t* ws = (uint8_t*)d_ws;
    size_t need = ACT_BYTES + WI8_BYTES + 1024;

    if (ws_size >= need) {
        uint8_t*  act  = ws;
        uint32_t* wI8  = (uint32_t*)(ws + ACT_BYTES);
        float*    invG = (float*)(ws + ACT_BYTES + WI8_BYTES);
        float*    b0G  = invG + P_;
        pack_act<<<N_ * ACT_NROWS, 256, 0, stream>>>(x, act);
        wpack_kernel<<<144, 256, 0, stream>>>(weight, bias, gamma, beta, mean, var, wI8, invG, b0G);
        bconv_pipe<<<32 * 14, 256, 0, stream>>>((const uint4*)wI8, invG, b0G, act, x, out);
    } else {
        uint32_t* wI8  = (uint32_t*)ws;
        float*    invG = (float*)(ws + WI8_BYTES);
        float*    b0G  = invG + P_;
        wpack_kernel<<<144, 256, 0, stream>>>(weight, bias, gamma, beta, mean, var, wI8, invG, b0G);
        bconv_fused<<<32 * 28, 256, 0, stream>>>((const uint4*)wI8, invG, b0G, x, out);
    }
}